// Round 3
// baseline (1570.375 us; speedup 1.0000x reference)
//
#include <hip/hip_runtime.h>
#include <stdint.h>

typedef unsigned short ushort_t;
typedef __attribute__((ext_vector_type(8))) short s16x8;
typedef __attribute__((ext_vector_type(4))) float f32x4;
typedef __attribute__((ext_vector_type(4))) unsigned short u16x4;

#define DEV __device__ __forceinline__

DEV ushort_t f2bf(float f) {
  union { float f; uint32_t u; } v; v.f = f;
  uint32_t r = (v.u + 0x7FFFu + ((v.u >> 16) & 1u)) >> 16;
  return (ushort_t)r;
}
DEV float bf2f(ushort_t u) {
  union { uint32_t u; float f; } v; v.u = ((uint32_t)u) << 16;
  return v.f;
}

#define GLD_LDS16(g, l)                                     \
  __builtin_amdgcn_global_load_lds(                         \
      (const __attribute__((address_space(1))) void*)(g),   \
      (__attribute__((address_space(3))) void*)(l), 16, 0, 0)

#define MFMA16(a, b, c) __builtin_amdgcn_mfma_f32_16x16x32_bf16((a), (b), (c), 0, 0, 0)

// ---------------- fp32 -> bf16 elementwise ----------------
__global__ __launch_bounds__(256) void k_conv(const float* __restrict__ in,
                                              ushort_t* __restrict__ out, int n4) {
  int i = blockIdx.x * 256 + threadIdx.x;
  if (i >= n4) return;
  float4 v = ((const float4*)in)[i];
  u16x4 o;
  o[0] = f2bf(v.x); o[1] = f2bf(v.y); o[2] = f2bf(v.z); o[3] = f2bf(v.w);
  *((u16x4*)out + i) = o;
}

// ------------- fp32 [R][C] -> bf16 [C][R] tiled transpose -------------
__global__ __launch_bounds__(256) void k_transpose_conv(const float* __restrict__ in,
                                                        ushort_t* __restrict__ out,
                                                        int R, int C) {
  __shared__ float tile[64][65];
  int c0 = blockIdx.x * 64, r0 = blockIdx.y * 64;
  int t = threadIdx.x;
#pragma unroll
  for (int i = 0; i < 4; ++i) {
    int e = (i * 256 + t) * 4;
    int rr = e >> 6, cc = e & 63;
    float4 v = *(const float4*)(in + (size_t)(r0 + rr) * C + (c0 + cc));
    tile[rr][cc] = v.x; tile[rr][cc + 1] = v.y;
    tile[rr][cc + 2] = v.z; tile[rr][cc + 3] = v.w;
  }
  __syncthreads();
#pragma unroll
  for (int i = 0; i < 4; ++i) {
    int e = (i * 256 + t) * 4;
    int cc = e >> 6, rr = e & 63;
    u16x4 o;
    o[0] = f2bf(tile[rr][cc]);     o[1] = f2bf(tile[rr + 1][cc]);
    o[2] = f2bf(tile[rr + 2][cc]); o[3] = f2bf(tile[rr + 3][cc]);
    *(u16x4*)(out + (size_t)(c0 + cc) * R + (r0 + rr)) = o;
  }
}

// ---------------- GEMM: C[M][N] = A[M][K] * Bt[N][K]^T (bf16 in, fp32 acc) ----------------
// 256x256 tile, BK=32, 512 threads = 8 waves (2M x 4N), per-wave 128x64 output.
// m201-style phase schedule: 2 phases per K-tile, each
//   {ds_read batch, 1 stage half, [vmcnt counted at phase B], s_barrier,
//    lgkmcnt(0)+sched_barrier, setprio(1), 16 MFMA, setprio(0), s_barrier}.
// 4-deep LDS ring, prefetch distance 3 K-tiles, vmcnt(8) steady state (never 0 in loop).
// LDS chunk swizzle: chunk ^= (row>>1)&3, applied on global SOURCE (linear LDS dest)
// and identically on the ds_read side -> measured 0 bank conflicts.
// ROPE: fused interleaved rotary on epilogue fp32 acc for cols < 8192 (q,k sections).
template <bool BF16OUT, bool ROPE>
__global__ __launch_bounds__(512, 2) void k_gemm_bt(const ushort_t* __restrict__ A,
                                                    const ushort_t* __restrict__ Bt,
                                                    ushort_t* __restrict__ Cb,
                                                    float* __restrict__ Cf,
                                                    const float* __restrict__ bias,
                                                    int M, int N, int K) {
  // 4 bufs x 256 rows x 32 cols bf16 = 64 KiB each matrix, 128 KiB total
  __shared__ __align__(16) ushort_t lA[4 * 256 * 32];
  __shared__ __align__(16) ushort_t lB[4 * 256 * 32];
  int t = threadIdx.x;
  int wv = t >> 6, lane = t & 63, quad = lane >> 4, lrow = lane & 15;
  int wr = wv >> 2, wc = wv & 3;

  // XCD-bijective block swizzle (grid sizes here are multiples of 8)
  int nbx = gridDim.x;
  int nwg = nbx * gridDim.y;
  int id = blockIdx.y * nbx + blockIdx.x;
  int qq = nwg >> 3;
  int sw = (id & 7) * qq + (id >> 3);
  int n0 = (sw % nbx) * 256;
  int m0 = (sw / nbx) * 256;

  // ---- staging constants: 512 slots per half-tile, slot = tid, row = tid>>2,
  // chunk_slot = tid&3, pre-swizzled global chunk = cs ^ ((row>>1)&3) = cs ^ ((tid>>3)&3)
  int srow = t >> 2;
  int gch = (t & 3) ^ ((t >> 3) & 3);
  const ushort_t* gA0 = A + (size_t)(m0 + srow) * K + gch * 8;
  const ushort_t* gA1 = gA0 + (size_t)128 * K;
  const ushort_t* gB0 = Bt + (size_t)(n0 + srow) * K + gch * 8;
  const ushort_t* gB1 = gB0 + (size_t)128 * K;
  int ldst = wv * 512;  // wave-uniform LDS slot base (elements); +4096 for half 1

  // ---- ds_read constants: logical chunk = quad, stored chunk = quad ^ ((row>>1)&3);
  // (row>>1)&3 == (lrow>>1)&3 since row = base16 + lrow (base16 multiple of 16)
  int xorv = (lrow >> 1) & 3;
  int aoff = (wr * 128 + lrow) * 32 + ((quad ^ xorv) * 8);
  int boff = (wc * 64 + lrow) * 32 + ((quad ^ xorv) * 8);

  f32x4 acc[8][4];
#pragma unroll
  for (int i = 0; i < 8; ++i)
#pragma unroll
    for (int j = 0; j < 4; ++j) acc[i][j] = (f32x4){0.f, 0.f, 0.f, 0.f};

  int nt = K >> 5;

  auto stageA = [&](int tt) {
    int buf = tt & 3;
    size_t ko = (size_t)tt * 32;
    ushort_t* la = lA + buf * 8192 + ldst;
    GLD_LDS16(gA0 + ko, la);
    GLD_LDS16(gA1 + ko, la + 4096);
  };
  auto stageB = [&](int tt) {
    int buf = tt & 3;
    size_t ko = (size_t)tt * 32;
    ushort_t* lb = lB + buf * 8192 + ldst;
    GLD_LDS16(gB0 + ko, lb);
    GLD_LDS16(gB1 + ko, lb + 4096);
  };

  s16x8 af[4], bfr[4];  // bfr persists across the two phases of a K-tile

#define PHASE_A(BUFV, DOSTAGE, TT)                                       \
  {                                                                      \
    const ushort_t* ba = lA + (BUFV) * 8192;                             \
    const ushort_t* bb = lB + (BUFV) * 8192;                             \
    _Pragma("unroll") for (int j = 0; j < 4; ++j)                        \
        bfr[j] = *(const s16x8*)(bb + boff + j * 512);                   \
    _Pragma("unroll") for (int i = 0; i < 4; ++i)                        \
        af[i] = *(const s16x8*)(ba + aoff + i * 512);                    \
    if (DOSTAGE) stageA((TT) + 3);                                       \
    __builtin_amdgcn_s_barrier();                                        \
    asm volatile("s_waitcnt lgkmcnt(0)" ::: "memory");                   \
    __builtin_amdgcn_sched_barrier(0);                                   \
    __builtin_amdgcn_s_setprio(1);                                       \
    _Pragma("unroll") for (int i = 0; i < 4; ++i)                        \
      _Pragma("unroll") for (int j = 0; j < 4; ++j)                      \
          acc[i][j] = MFMA16(af[i], bfr[j], acc[i][j]);                  \
    __builtin_amdgcn_s_setprio(0);                                       \
    __builtin_amdgcn_s_barrier();                                        \
  }

#define PHASE_B(BUFV, DOSTAGE, TT, VMWAIT)                               \
  {                                                                      \
    const ushort_t* ba = lA + (BUFV) * 8192;                             \
    _Pragma("unroll") for (int i = 0; i < 4; ++i)                        \
        af[i] = *(const s16x8*)(ba + aoff + (i + 4) * 512);              \
    if (DOSTAGE) stageB((TT) + 3);                                       \
    VMWAIT;                                                              \
    __builtin_amdgcn_s_barrier();                                        \
    asm volatile("s_waitcnt lgkmcnt(0)" ::: "memory");                   \
    __builtin_amdgcn_sched_barrier(0);                                   \
    __builtin_amdgcn_s_setprio(1);                                       \
    _Pragma("unroll") for (int i = 0; i < 4; ++i)                        \
      _Pragma("unroll") for (int j = 0; j < 4; ++j)                      \
          acc[i + 4][j] = MFMA16(af[i], bfr[j], acc[i + 4][j]);          \
    __builtin_amdgcn_s_setprio(0);                                       \
    __builtin_amdgcn_s_barrier();                                        \
  }

  // prologue: stage tiles 0,1,2 (12 loads/thread); land tile 0 (oldest 4) before reads.
  stageA(0); stageB(0);
  stageA(1); stageB(1);
  stageA(2); stageB(2);
  asm volatile("s_waitcnt vmcnt(8)" ::: "memory");
  __builtin_amdgcn_s_barrier();

  // main loop: at tile t phase B, newest 8 outstanding = tiles t+2,t+3 loads ->
  // vmcnt(8) lands tile t+1 (read next phase) while 8 loads stay in flight.
  for (int tt = 0; tt < nt - 3; ++tt) {
    PHASE_A(tt & 3, true, tt);
    PHASE_B(tt & 3, true, tt, asm volatile("s_waitcnt vmcnt(8)" ::: "memory"));
  }
  // epilogue drain: 8 -> 4 -> 0 -> none
  PHASE_A((nt - 3) & 3, false, 0);
  PHASE_B((nt - 3) & 3, false, 0, asm volatile("s_waitcnt vmcnt(4)" ::: "memory"));
  PHASE_A((nt - 2) & 3, false, 0);
  PHASE_B((nt - 2) & 3, false, 0, asm volatile("s_waitcnt vmcnt(0)" ::: "memory"));
  PHASE_A((nt - 1) & 3, false, 0);
  PHASE_B((nt - 1) & 3, false, 0, (void)0);
#undef PHASE_A
#undef PHASE_B

  // ---- epilogue ----
  bool do_rope = ROPE && (n0 < 8192);  // block-uniform (8192 % 256 == 0)
  float sgn_sel = (lrow & 1) ? 1.f : -1.f;
#pragma unroll
  for (int j = 0; j < 4; ++j) {
    int gc = n0 + wc * 64 + j * 16 + lrow;
    float freq = 0.f;
    if (do_rope) {
      int p = (gc & 127) >> 1;
      freq = __expf(-(float)p * 0.14391156509165667f);  // ln(1e4)/64
    }
#pragma unroll
    for (int i = 0; i < 8; ++i)
#pragma unroll
      for (int r = 0; r < 4; ++r) {
        int gr = m0 + wr * 128 + i * 16 + quad * 4 + r;
        float val = acc[i][j][r];
        if (do_rope) {
          float other = __shfl_xor(val, 1);
          float sv, cv;
          sincosf((float)(gr & 2047) * freq, &sv, &cv);
          val = fmaf(other, sgn_sel * sv, val * cv);
        }
        if (BF16OUT)
          Cb[(size_t)gr * N + gc] = f2bf(val);
        else
          Cf[(size_t)gr * N + gc] = val + bias[gc];
      }
  }
}

// ---------------- build V^T: vt[b,h,d,s] from qkv v-section ----------------
__global__ __launch_bounds__(256) void k_build_vt(const ushort_t* __restrict__ qkv,
                                                  ushort_t* __restrict__ vt) {
  const int S = 2048;
  int s0 = blockIdx.x * 64;
  int bh = blockIdx.y;
  int b = bh >> 5, h = bh & 31;
  __shared__ ushort_t tl[64][136];
  int t = threadIdx.x;
  const ushort_t* src = qkv + (size_t)(b * S + s0) * 12288 + 8192 + h * 128;
#pragma unroll
  for (int i = 0; i < 4; ++i) {
    int e = (i * 256 + t) * 8;
    int row = e >> 7, col = e & 127;
    *(s16x8*)&tl[row][col] = *(const s16x8*)(src + (size_t)row * 12288 + col);
  }
  __syncthreads();
  ushort_t* dst = vt + (size_t)bh * 128 * S;
#pragma unroll
  for (int i = 0; i < 4; ++i) {
    int e = (i * 256 + t) * 8;
    int d = e >> 6, ss = e & 63;
    s16x8 o;
#pragma unroll
    for (int j = 0; j < 8; ++j) o[j] = (short)tl[ss + j][d];
    *(s16x8*)(dst + (size_t)d * S + s0 + ss) = o;
  }
}

// ---------------- causal flash attention ----------------
// grid: (S/128, B*H). block 256 = 4 waves; wave wv owns q rows [q0+32wv, +32).
// Q in registers; K/V staged via global_load_lds w/ XOR swizzle; 2 barriers/iter.
__global__ __launch_bounds__(256, 2) void k_attn(const ushort_t* __restrict__ qkv,
                                                 const ushort_t* __restrict__ vt,
                                                 ushort_t* __restrict__ ctx) {
  const int S = 2048;
  int qt = blockIdx.x, bh = blockIdx.y;
  int b = bh >> 5, h = bh & 31;
  int q0 = qt * 128;
  int t = threadIdx.x;
  int wv = t >> 6, lane = t & 63, quad = lane >> 4, lrow = lane & 15;

  __shared__ ushort_t lK[64 * 128];   // [kv][d], swizzled 16B chunks
  __shared__ ushort_t lV[128 * 64];   // [d][kv], swizzled 16B chunks
  __shared__ ushort_t lP[4][32][72];  // per-wave P round-trip (C-layout -> A-layout)

  const ushort_t* qp = qkv + (size_t)(b * S) * 12288 + h * 128;
  const ushort_t* kp = qp + 4096;
  const ushort_t* vp = vt + (size_t)bh * 128 * S;

  // Q fragments in registers (rope already applied by fused GEMM epilogue)
  s16x8 qf[2][4];
  int qrb = q0 + wv * 32;
#pragma unroll
  for (int ti = 0; ti < 2; ++ti)
#pragma unroll
    for (int ks = 0; ks < 4; ++ks)
      qf[ti][ks] = *(const s16x8*)(qp + (size_t)(qrb + ti * 16 + lrow) * 12288 +
                                   ks * 32 + quad * 8);

  f32x4 O[2][8];
#pragma unroll
  for (int ti = 0; ti < 2; ++ti)
#pragma unroll
    for (int f = 0; f < 8; ++f) O[ti][f] = (f32x4){0.f, 0.f, 0.f, 0.f};
  float m_i[2][4], l_i[2][4];
#pragma unroll
  for (int ti = 0; ti < 2; ++ti)
#pragma unroll
    for (int r = 0; r < 4; ++r) { m_i[ti][r] = -__builtin_inff(); l_i[ti][r] = 0.f; }

  const float scale = 0.08838834764831845f;  // 1/sqrt(128)
  int qhi = q0 + 127;

  for (int kv0 = 0; kv0 <= qhi; kv0 += 64) {
    __syncthreads();  // prior iter's lK/lV reads done before restage
    {
      int ck = lane & 15;
      int cv = lane & 7;
#pragma unroll
      for (int it = 0; it < 4; ++it) {
        int slot = wv * 4 + it;
        // K: 1024B = 4 rows of 256B; lane -> row slot*4+(lane>>4), chunk lane&15
        int rowk = slot * 4 + (lane >> 4);
        int cpk = (ck & 8) | ((ck & 7) ^ (rowk & 7));
        GLD_LDS16(kp + (size_t)(kv0 + rowk) * 12288 + cpk * 8, lK + slot * 512);
        // V^T: 1024B = 8 rows of 128B; lane -> row slot*8+(lane>>3), chunk lane&7
        int rowv = slot * 8 + (lane >> 3);
        int cpv = cv ^ (rowv & 7);
        GLD_LDS16(vp + (size_t)rowv * S + kv0 + cpv * 8, lV + slot * 512);
      }
    }
    __syncthreads();

    // S_tile = Q_tile @ K_tile^T
    f32x4 sc[2][4];
#pragma unroll
    for (int ti = 0; ti < 2; ++ti)
#pragma unroll
      for (int nt = 0; nt < 4; ++nt) sc[ti][nt] = (f32x4){0.f, 0.f, 0.f, 0.f};
#pragma unroll
    for (int ks = 0; ks < 4; ++ks) {
      s16x8 bk[4];
#pragma unroll
      for (int nt = 0; nt < 4; ++nt) {
        int row = nt * 16 + lrow;
        int cc = ks * 4 + quad;
        int cp = (cc & 8) | ((cc & 7) ^ (row & 7));
        bk[nt] = *(const s16x8*)(lK + row * 128 + cp * 8);
      }
#pragma unroll
      for (int ti = 0; ti < 2; ++ti)
#pragma unroll
        for (int nt = 0; nt < 4; ++nt) sc[ti][nt] = MFMA16(qf[ti][ks], bk[nt], sc[ti][nt]);
    }

    // online softmax per 16-row tile (C layout: row = quad*4+r, col = lrow)
#pragma unroll
    for (int ti = 0; ti < 2; ++ti) {
      int qr = qrb + ti * 16 + quad * 4;
      float mt[4];
#pragma unroll
      for (int r = 0; r < 4; ++r) mt[r] = -__builtin_inff();
      float pvl[4][4];
#pragma unroll
      for (int nt = 0; nt < 4; ++nt) {
        int kc = kv0 + nt * 16 + lrow;
#pragma unroll
        for (int r = 0; r < 4; ++r) {
          float sv = sc[ti][nt][r] * scale;
          if (kc > qr + r) sv = -__builtin_inff();
          pvl[nt][r] = sv;
          mt[r] = fmaxf(mt[r], sv);
        }
      }
#pragma unroll
      for (int r = 0; r < 4; ++r)
#pragma unroll
        for (int off = 1; off < 16; off <<= 1)
          mt[r] = fmaxf(mt[r], __shfl_xor(mt[r], off, 16));

      float al[4], ls[4];
#pragma unroll
      for (int r = 0; r < 4; ++r) {
        float mn = fmaxf(m_i[ti][r], mt[r]);
        al[r] = __expf(m_i[ti][r] - mn);
        m_i[ti][r] = mn;
        ls[r] = 0.f;
      }
#pragma unroll
      for (int nt = 0; nt < 4; ++nt)
#pragma unroll
        for (int r = 0; r < 4; ++r) {
          float p = __expf(pvl[nt][r] - m_i[ti][r]);
          ushort_t pu = f2bf(p);
          lP[wv][ti * 16 + quad * 4 + r][nt * 16 + lrow] = pu;
          ls[r] += bf2f(pu);  // denominator from the same rounded P the PV mfma sees
        }
#pragma unroll
      for (int r = 0; r < 4; ++r) {
#pragma unroll
        for (int off = 1; off < 16; off <<= 1) ls[r] += __shfl_xor(ls[r], off, 16);
        l_i[ti][r] = al[r] * l_i[ti][r] + ls[r];
      }
#pragma unroll
      for (int f = 0; f < 8; ++f)
#pragma unroll
        for (int r = 0; r < 4; ++r) O[ti][f][r] *= al[r];
    }
    // NOTE: no barrier here — lP[wv] is same-wave write->read; lgkmcnt covers it.

    // O += P @ V
#pragma unroll
    for (int ks = 0; ks < 2; ++ks) {
      s16x8 pa[2];
#pragma unroll
      for (int ti = 0; ti < 2; ++ti)
        pa[ti] = *(const s16x8*)&lP[wv][ti * 16 + lrow][ks * 32 + quad * 8];
#pragma unroll
      for (int f = 0; f < 8; ++f) {
        int row = f * 16 + lrow;
        int cc = ks * 4 + quad;
        int cp = cc ^ (row & 7);
        s16x8 bv = *(const s16x8*)(lV + row * 64 + cp * 8);
#pragma unroll
        for (int ti = 0; ti < 2; ++ti) O[ti][f] = MFMA16(pa[ti], bv, O[ti][f]);
      }
    }
  }

#pragma unroll
  for (int ti = 0; ti < 2; ++ti) {
    float inv[4];
#pragma unroll
    for (int r = 0; r < 4; ++r) inv[r] = 1.f / l_i[ti][r];
#pragma unroll
    for (int f = 0; f < 8; ++f)
#pragma unroll
      for (int r = 0; r < 4; ++r) {
        size_t idx = (size_t)(b * S + qrb + ti * 16 + quad * 4 + r) * 4096 +
                     h * 128 + f * 16 + lrow;
        ctx[idx] = f2bf(O[ti][f][r] * inv[r]);
      }
  }
}

// ---------------- launcher ----------------
extern "C" void kernel_launch(void* const* d_in, const int* in_sizes, int n_in,
                              void* d_out, int out_size, void* d_ws, size_t ws_size,
                              hipStream_t stream) {
  const float* x      = (const float*)d_in[0];  // [2,2048,4096]
  const float* w_qkv  = (const float*)d_in[1];  // [4096,12288]
  const float* w_proj = (const float*)d_in[2];  // [4096,4096]
  const float* b_proj = (const float*)d_in[3];  // [4096]
  float* out = (float*)d_out;

  char* ws = (char*)d_ws;
  ushort_t* xb     = (ushort_t*)(ws);                 // 33,554,432 B
  ushort_t* wqkvt  = (ushort_t*)(ws + 33554432ULL);   // 100,663,296 B  [12288][4096]
  ushort_t* wprojt = (ushort_t*)(ws + 134217728ULL);  // 33,554,432 B   [4096][4096]
  ushort_t* qkvb   = (ushort_t*)(ws + 167772160ULL);  // 100,663,296 B  [4096][12288]
  ushort_t* vt     = (ushort_t*)(ws + 268435456ULL);  // 33,554,432 B   [64][128][2048]
  ushort_t* ctx    = (ushort_t*)(ws + 301989888ULL);  // 33,554,432 B   [4096][4096]

  k_conv<<<16384, 256, 0, stream>>>(x, xb, 16777216 / 4);
  k_transpose_conv<<<dim3(192, 64), 256, 0, stream>>>(w_qkv, wqkvt, 4096, 12288);
  k_transpose_conv<<<dim3(64, 64), 256, 0, stream>>>(w_proj, wprojt, 4096, 4096);
  k_gemm_bt<true, true><<<dim3(48, 16), 512, 0, stream>>>(xb, wqkvt, qkvb, nullptr,
                                                          nullptr, 4096, 12288, 4096);
  k_build_vt<<<dim3(32, 64), 256, 0, stream>>>(qkvb, vt);
  k_attn<<<dim3(16, 64), 256, 0, stream>>>(qkvb, vt, ctx);
  k_gemm_bt<false, false><<<dim3(16, 16), 512, 0, stream>>>(ctx, wprojt, nullptr, out,
                                                            b_proj, 4096, 4096, 4096);
}

// Round 4
// 1453.495 us; speedup vs baseline: 1.0804x; 1.0804x over previous
//
#include <hip/hip_runtime.h>
#include <stdint.h>

typedef unsigned short ushort_t;
typedef __attribute__((ext_vector_type(8))) short s16x8;
typedef __attribute__((ext_vector_type(4))) float f32x4;
typedef __attribute__((ext_vector_type(4))) unsigned short u16x4;

#define DEV __device__ __forceinline__

DEV ushort_t f2bf(float f) {
  union { float f; uint32_t u; } v; v.f = f;
  uint32_t r = (v.u + 0x7FFFu + ((v.u >> 16) & 1u)) >> 16;
  return (ushort_t)r;
}
DEV float bf2f(ushort_t u) {
  union { uint32_t u; float f; } v; v.u = ((uint32_t)u) << 16;
  return v.f;
}

#define GLD_LDS16(g, l)                                     \
  __builtin_amdgcn_global_load_lds(                         \
      (const __attribute__((address_space(1))) void*)(g),   \
      (__attribute__((address_space(3))) void*)(l), 16, 0, 0)

#define MFMA16(a, b, c) __builtin_amdgcn_mfma_f32_16x16x32_bf16((a), (b), (c), 0, 0, 0)

// ---------------- fp32 -> bf16 elementwise ----------------
__global__ __launch_bounds__(256) void k_conv(const float* __restrict__ in,
                                              ushort_t* __restrict__ out, int n4) {
  int i = blockIdx.x * 256 + threadIdx.x;
  if (i >= n4) return;
  float4 v = ((const float4*)in)[i];
  u16x4 o;
  o[0] = f2bf(v.x); o[1] = f2bf(v.y); o[2] = f2bf(v.z); o[3] = f2bf(v.w);
  *((u16x4*)out + i) = o;
}

// ------------- fp32 [R][C] -> bf16 [C][R] tiled transpose -------------
__global__ __launch_bounds__(256) void k_transpose_conv(const float* __restrict__ in,
                                                        ushort_t* __restrict__ out,
                                                        int R, int C) {
  __shared__ float tile[64][65];
  int c0 = blockIdx.x * 64, r0 = blockIdx.y * 64;
  int t = threadIdx.x;
#pragma unroll
  for (int i = 0; i < 4; ++i) {
    int e = (i * 256 + t) * 4;
    int rr = e >> 6, cc = e & 63;
    float4 v = *(const float4*)(in + (size_t)(r0 + rr) * C + (c0 + cc));
    tile[rr][cc] = v.x; tile[rr][cc + 1] = v.y;
    tile[rr][cc + 2] = v.z; tile[rr][cc + 3] = v.w;
  }
  __syncthreads();
#pragma unroll
  for (int i = 0; i < 4; ++i) {
    int e = (i * 256 + t) * 4;
    int cc = e >> 6, rr = e & 63;
    u16x4 o;
    o[0] = f2bf(tile[rr][cc]);     o[1] = f2bf(tile[rr + 1][cc]);
    o[2] = f2bf(tile[rr + 2][cc]); o[3] = f2bf(tile[rr + 3][cc]);
    *(u16x4*)(out + (size_t)(c0 + cc) * R + (r0 + rr)) = o;
  }
}

// ---------------- GEMM: C[M][N] = A[M][K] * Bt[N][K]^T (bf16 in, fp32 acc) ----------------
// 256x256 tile, BK=32, 512 threads = 8 waves (2M x 4N), per-wave 128x64 output.
// m201-style phase schedule: 2 phases per K-tile, each
//   {ds_read batch, 1 stage half, [vmcnt counted at phase B], s_barrier,
//    lgkmcnt(0), setprio(1), 16 MFMA, setprio(0), s_barrier}.
// NOTE: no sched_barrier(0) — m141-class order-pinning regressed this kernel 543->739us
// in round 3; compiler-visible ds_reads are already ordered vs MFMA by the compiler.
// 4-deep LDS ring, prefetch distance 3 K-tiles, vmcnt(8) steady state (never 0 in loop).
// LDS chunk swizzle: chunk ^= (row>>1)&3, applied on global SOURCE (linear LDS dest)
// and identically on the ds_read side -> measured 0 bank conflicts.
// ROPE: fused interleaved rotary on epilogue fp32 acc for cols < 8192 (q,k sections).
template <bool BF16OUT, bool ROPE>
__global__ __launch_bounds__(512, 2) void k_gemm_bt(const ushort_t* __restrict__ A,
                                                    const ushort_t* __restrict__ Bt,
                                                    ushort_t* __restrict__ Cb,
                                                    float* __restrict__ Cf,
                                                    const float* __restrict__ bias,
                                                    int M, int N, int K) {
  // 4 bufs x 256 rows x 32 cols bf16 = 64 KiB each matrix, 128 KiB total
  __shared__ __align__(16) ushort_t lA[4 * 256 * 32];
  __shared__ __align__(16) ushort_t lB[4 * 256 * 32];
  int t = threadIdx.x;
  int wv = t >> 6, lane = t & 63, quad = lane >> 4, lrow = lane & 15;
  int wr = wv >> 2, wc = wv & 3;

  // XCD-bijective block swizzle (grid sizes here are multiples of 8)
  int nbx = gridDim.x;
  int nwg = nbx * gridDim.y;
  int id = blockIdx.y * nbx + blockIdx.x;
  int qq = nwg >> 3;
  int sw = (id & 7) * qq + (id >> 3);
  int n0 = (sw % nbx) * 256;
  int m0 = (sw / nbx) * 256;

  // ---- staging constants: 512 slots per half-tile, slot = tid, row = tid>>2,
  // chunk_slot = tid&3, pre-swizzled global chunk = cs ^ ((row>>1)&3) = cs ^ ((tid>>3)&3)
  int srow = t >> 2;
  int gch = (t & 3) ^ ((t >> 3) & 3);
  const ushort_t* gA0 = A + (size_t)(m0 + srow) * K + gch * 8;
  const ushort_t* gA1 = gA0 + (size_t)128 * K;
  const ushort_t* gB0 = Bt + (size_t)(n0 + srow) * K + gch * 8;
  const ushort_t* gB1 = gB0 + (size_t)128 * K;
  int ldst = wv * 512;  // wave-uniform LDS slot base (elements); +4096 for half 1

  // ---- ds_read constants: logical chunk = quad, stored chunk = quad ^ ((row>>1)&3);
  // (row>>1)&3 == (lrow>>1)&3 since row = base16 + lrow (base16 multiple of 16)
  int xorv = (lrow >> 1) & 3;
  int aoff = (wr * 128 + lrow) * 32 + ((quad ^ xorv) * 8);
  int boff = (wc * 64 + lrow) * 32 + ((quad ^ xorv) * 8);

  f32x4 acc[8][4];
#pragma unroll
  for (int i = 0; i < 8; ++i)
#pragma unroll
    for (int j = 0; j < 4; ++j) acc[i][j] = (f32x4){0.f, 0.f, 0.f, 0.f};

  int nt = K >> 5;

  auto stageA = [&](int tt) {
    int buf = tt & 3;
    size_t ko = (size_t)tt * 32;
    ushort_t* la = lA + buf * 8192 + ldst;
    GLD_LDS16(gA0 + ko, la);
    GLD_LDS16(gA1 + ko, la + 4096);
  };
  auto stageB = [&](int tt) {
    int buf = tt & 3;
    size_t ko = (size_t)tt * 32;
    ushort_t* lb = lB + buf * 8192 + ldst;
    GLD_LDS16(gB0 + ko, lb);
    GLD_LDS16(gB1 + ko, lb + 4096);
  };

  s16x8 af[4], bfr[4];  // bfr persists across the two phases of a K-tile

#define PHASE_A(BUFV, DOSTAGE, TT)                                       \
  {                                                                      \
    const ushort_t* ba = lA + (BUFV) * 8192;                             \
    const ushort_t* bb = lB + (BUFV) * 8192;                             \
    _Pragma("unroll") for (int j = 0; j < 4; ++j)                        \
        bfr[j] = *(const s16x8*)(bb + boff + j * 512);                   \
    _Pragma("unroll") for (int i = 0; i < 4; ++i)                        \
        af[i] = *(const s16x8*)(ba + aoff + i * 512);                    \
    if (DOSTAGE) stageA((TT) + 3);                                       \
    __builtin_amdgcn_s_barrier();                                        \
    asm volatile("s_waitcnt lgkmcnt(0)" ::: "memory");                   \
    __builtin_amdgcn_s_setprio(1);                                       \
    _Pragma("unroll") for (int i = 0; i < 4; ++i)                        \
      _Pragma("unroll") for (int j = 0; j < 4; ++j)                      \
          acc[i][j] = MFMA16(af[i], bfr[j], acc[i][j]);                  \
    __builtin_amdgcn_s_setprio(0);                                       \
    __builtin_amdgcn_s_barrier();                                        \
  }

#define PHASE_B(BUFV, DOSTAGE, TT, VMWAIT)                               \
  {                                                                      \
    const ushort_t* ba = lA + (BUFV) * 8192;                             \
    _Pragma("unroll") for (int i = 0; i < 4; ++i)                        \
        af[i] = *(const s16x8*)(ba + aoff + (i + 4) * 512);              \
    if (DOSTAGE) stageB((TT) + 3);                                       \
    VMWAIT;                                                              \
    __builtin_amdgcn_s_barrier();                                        \
    asm volatile("s_waitcnt lgkmcnt(0)" ::: "memory");                   \
    __builtin_amdgcn_s_setprio(1);                                       \
    _Pragma("unroll") for (int i = 0; i < 4; ++i)                        \
      _Pragma("unroll") for (int j = 0; j < 4; ++j)                      \
          acc[i + 4][j] = MFMA16(af[i], bfr[j], acc[i + 4][j]);          \
    __builtin_amdgcn_s_setprio(0);                                       \
    __builtin_amdgcn_s_barrier();                                        \
  }

  // prologue: stage tiles 0,1,2 (12 loads/thread); land tile 0 (oldest 4) before reads.
  stageA(0); stageB(0);
  stageA(1); stageB(1);
  stageA(2); stageB(2);
  asm volatile("s_waitcnt vmcnt(8)" ::: "memory");
  __builtin_amdgcn_s_barrier();

  // main loop: at tile t phase B, newest 8 outstanding = tiles t+2,t+3 loads ->
  // vmcnt(8) lands tile t+1 (read next phase) while 8 loads stay in flight.
  for (int tt = 0; tt < nt - 3; ++tt) {
    PHASE_A(tt & 3, true, tt);
    PHASE_B(tt & 3, true, tt, asm volatile("s_waitcnt vmcnt(8)" ::: "memory"));
  }
  // epilogue drain: 8 -> 4 -> 0 -> none
  PHASE_A((nt - 3) & 3, false, 0);
  PHASE_B((nt - 3) & 3, false, 0, asm volatile("s_waitcnt vmcnt(4)" ::: "memory"));
  PHASE_A((nt - 2) & 3, false, 0);
  PHASE_B((nt - 2) & 3, false, 0, asm volatile("s_waitcnt vmcnt(0)" ::: "memory"));
  PHASE_A((nt - 1) & 3, false, 0);
  PHASE_B((nt - 1) & 3, false, 0, (void)0);
#undef PHASE_A
#undef PHASE_B

  // ---- epilogue ----
  bool do_rope = ROPE && (n0 < 8192);  // block-uniform (8192 % 256 == 0)
  float sgn_sel = (lrow & 1) ? 1.f : -1.f;
#pragma unroll
  for (int j = 0; j < 4; ++j) {
    int gc = n0 + wc * 64 + j * 16 + lrow;
    float freq = 0.f;
    if (do_rope) {
      int p = (gc & 127) >> 1;
      freq = __expf(-(float)p * 0.14391156509165667f);  // ln(1e4)/64
    }
#pragma unroll
    for (int i = 0; i < 8; ++i)
#pragma unroll
      for (int r = 0; r < 4; ++r) {
        int gr = m0 + wr * 128 + i * 16 + quad * 4 + r;
        float val = acc[i][j][r];
        if (do_rope) {
          float other = __shfl_xor(val, 1);
          float sv, cv;
          sincosf((float)(gr & 2047) * freq, &sv, &cv);
          val = fmaf(other, sgn_sel * sv, val * cv);
        }
        if (BF16OUT)
          Cb[(size_t)gr * N + gc] = f2bf(val);
        else
          Cf[(size_t)gr * N + gc] = val + bias[gc];
      }
  }
}

// ---------------- build V^T: vt[b,h,d,s] from qkv v-section ----------------
__global__ __launch_bounds__(256) void k_build_vt(const ushort_t* __restrict__ qkv,
                                                  ushort_t* __restrict__ vt) {
  const int S = 2048;
  int s0 = blockIdx.x * 64;
  int bh = blockIdx.y;
  int b = bh >> 5, h = bh & 31;
  __shared__ ushort_t tl[64][136];
  int t = threadIdx.x;
  const ushort_t* src = qkv + (size_t)(b * S + s0) * 12288 + 8192 + h * 128;
#pragma unroll
  for (int i = 0; i < 4; ++i) {
    int e = (i * 256 + t) * 8;
    int row = e >> 7, col = e & 127;
    *(s16x8*)&tl[row][col] = *(const s16x8*)(src + (size_t)row * 12288 + col);
  }
  __syncthreads();
  ushort_t* dst = vt + (size_t)bh * 128 * S;
#pragma unroll
  for (int i = 0; i < 4; ++i) {
    int e = (i * 256 + t) * 8;
    int d = e >> 6, ss = e & 63;
    s16x8 o;
#pragma unroll
    for (int j = 0; j < 8; ++j) o[j] = (short)tl[ss + j][d];
    *(s16x8*)(dst + (size_t)d * S + s0 + ss) = o;
  }
}

// ---------------- causal flash attention ----------------
// grid: (S/128, B*H). block 256 = 4 waves; wave wv owns q rows [q0+32wv, +32).
// Q in registers; K/V staged via global_load_lds w/ XOR swizzle; 2 barriers/iter.
__global__ __launch_bounds__(256, 2) void k_attn(const ushort_t* __restrict__ qkv,
                                                 const ushort_t* __restrict__ vt,
                                                 ushort_t* __restrict__ ctx) {
  const int S = 2048;
  int qt = blockIdx.x, bh = blockIdx.y;
  int b = bh >> 5, h = bh & 31;
  int q0 = qt * 128;
  int t = threadIdx.x;
  int wv = t >> 6, lane = t & 63, quad = lane >> 4, lrow = lane & 15;

  __shared__ ushort_t lK[64 * 128];   // [kv][d], swizzled 16B chunks
  __shared__ ushort_t lV[128 * 64];   // [d][kv], swizzled 16B chunks
  __shared__ ushort_t lP[4][32][72];  // per-wave P round-trip (C-layout -> A-layout)

  const ushort_t* qp = qkv + (size_t)(b * S) * 12288 + h * 128;
  const ushort_t* kp = qp + 4096;
  const ushort_t* vp = vt + (size_t)bh * 128 * S;

  // Q fragments in registers (rope already applied by fused GEMM epilogue)
  s16x8 qf[2][4];
  int qrb = q0 + wv * 32;
#pragma unroll
  for (int ti = 0; ti < 2; ++ti)
#pragma unroll
    for (int ks = 0; ks < 4; ++ks)
      qf[ti][ks] = *(const s16x8*)(qp + (size_t)(qrb + ti * 16 + lrow) * 12288 +
                                   ks * 32 + quad * 8);

  f32x4 O[2][8];
#pragma unroll
  for (int ti = 0; ti < 2; ++ti)
#pragma unroll
    for (int f = 0; f < 8; ++f) O[ti][f] = (f32x4){0.f, 0.f, 0.f, 0.f};
  float m_i[2][4], l_i[2][4];
#pragma unroll
  for (int ti = 0; ti < 2; ++ti)
#pragma unroll
    for (int r = 0; r < 4; ++r) { m_i[ti][r] = -__builtin_inff(); l_i[ti][r] = 0.f; }

  const float scale = 0.08838834764831845f;  // 1/sqrt(128)
  int qhi = q0 + 127;

  for (int kv0 = 0; kv0 <= qhi; kv0 += 64) {
    __syncthreads();  // prior iter's lK/lV reads done before restage
    {
      int ck = lane & 15;
      int cv = lane & 7;
#pragma unroll
      for (int it = 0; it < 4; ++it) {
        int slot = wv * 4 + it;
        // K: 1024B = 4 rows of 256B; lane -> row slot*4+(lane>>4), chunk lane&15
        int rowk = slot * 4 + (lane >> 4);
        int cpk = (ck & 8) | ((ck & 7) ^ (rowk & 7));
        GLD_LDS16(kp + (size_t)(kv0 + rowk) * 12288 + cpk * 8, lK + slot * 512);
        // V^T: 1024B = 8 rows of 128B; lane -> row slot*8+(lane>>3), chunk lane&7
        int rowv = slot * 8 + (lane >> 3);
        int cpv = cv ^ (rowv & 7);
        GLD_LDS16(vp + (size_t)rowv * S + kv0 + cpv * 8, lV + slot * 512);
      }
    }
    __syncthreads();

    // S_tile = Q_tile @ K_tile^T
    f32x4 sc[2][4];
#pragma unroll
    for (int ti = 0; ti < 2; ++ti)
#pragma unroll
      for (int nt = 0; nt < 4; ++nt) sc[ti][nt] = (f32x4){0.f, 0.f, 0.f, 0.f};
#pragma unroll
    for (int ks = 0; ks < 4; ++ks) {
      s16x8 bk[4];
#pragma unroll
      for (int nt = 0; nt < 4; ++nt) {
        int row = nt * 16 + lrow;
        int cc = ks * 4 + quad;
        int cp = (cc & 8) | ((cc & 7) ^ (row & 7));
        bk[nt] = *(const s16x8*)(lK + row * 128 + cp * 8);
      }
#pragma unroll
      for (int ti = 0; ti < 2; ++ti)
#pragma unroll
        for (int nt = 0; nt < 4; ++nt) sc[ti][nt] = MFMA16(qf[ti][ks], bk[nt], sc[ti][nt]);
    }

    // online softmax per 16-row tile (C layout: row = quad*4+r, col = lrow)
#pragma unroll
    for (int ti = 0; ti < 2; ++ti) {
      int qr = qrb + ti * 16 + quad * 4;
      float mt[4];
#pragma unroll
      for (int r = 0; r < 4; ++r) mt[r] = -__builtin_inff();
      float pvl[4][4];
#pragma unroll
      for (int nt = 0; nt < 4; ++nt) {
        int kc = kv0 + nt * 16 + lrow;
#pragma unroll
        for (int r = 0; r < 4; ++r) {
          float sv = sc[ti][nt][r] * scale;
          if (kc > qr + r) sv = -__builtin_inff();
          pvl[nt][r] = sv;
          mt[r] = fmaxf(mt[r], sv);
        }
      }
#pragma unroll
      for (int r = 0; r < 4; ++r)
#pragma unroll
        for (int off = 1; off < 16; off <<= 1)
          mt[r] = fmaxf(mt[r], __shfl_xor(mt[r], off, 16));

      float al[4], ls[4];
#pragma unroll
      for (int r = 0; r < 4; ++r) {
        float mn = fmaxf(m_i[ti][r], mt[r]);
        al[r] = __expf(m_i[ti][r] - mn);
        m_i[ti][r] = mn;
        ls[r] = 0.f;
      }
#pragma unroll
      for (int nt = 0; nt < 4; ++nt)
#pragma unroll
        for (int r = 0; r < 4; ++r) {
          float p = __expf(pvl[nt][r] - m_i[ti][r]);
          ushort_t pu = f2bf(p);
          lP[wv][ti * 16 + quad * 4 + r][nt * 16 + lrow] = pu;
          ls[r] += bf2f(pu);  // denominator from the same rounded P the PV mfma sees
        }
#pragma unroll
      for (int r = 0; r < 4; ++r) {
#pragma unroll
        for (int off = 1; off < 16; off <<= 1) ls[r] += __shfl_xor(ls[r], off, 16);
        l_i[ti][r] = al[r] * l_i[ti][r] + ls[r];
      }
#pragma unroll
      for (int f = 0; f < 8; ++f)
#pragma unroll
        for (int r = 0; r < 4; ++r) O[ti][f][r] *= al[r];
    }
    // NOTE: no barrier here — lP[wv] is same-wave write->read; lgkmcnt covers it.

    // O += P @ V
#pragma unroll
    for (int ks = 0; ks < 2; ++ks) {
      s16x8 pa[2];
#pragma unroll
      for (int ti = 0; ti < 2; ++ti)
        pa[ti] = *(const s16x8*)&lP[wv][ti * 16 + lrow][ks * 32 + quad * 8];
#pragma unroll
      for (int f = 0; f < 8; ++f) {
        int row = f * 16 + lrow;
        int cc = ks * 4 + quad;
        int cp = cc ^ (row & 7);
        s16x8 bv = *(const s16x8*)(lV + row * 64 + cp * 8);
#pragma unroll
        for (int ti = 0; ti < 2; ++ti) O[ti][f] = MFMA16(pa[ti], bv, O[ti][f]);
      }
    }
  }

#pragma unroll
  for (int ti = 0; ti < 2; ++ti) {
    float inv[4];
#pragma unroll
    for (int r = 0; r < 4; ++r) inv[r] = 1.f / l_i[ti][r];
#pragma unroll
    for (int f = 0; f < 8; ++f)
#pragma unroll
      for (int r = 0; r < 4; ++r) {
        size_t idx = (size_t)(b * S + qrb + ti * 16 + quad * 4 + r) * 4096 +
                     h * 128 + f * 16 + lrow;
        ctx[idx] = f2bf(O[ti][f][r] * inv[r]);
      }
  }
}

// ---------------- launcher ----------------
extern "C" void kernel_launch(void* const* d_in, const int* in_sizes, int n_in,
                              void* d_out, int out_size, void* d_ws, size_t ws_size,
                              hipStream_t stream) {
  const float* x      = (const float*)d_in[0];  // [2,2048,4096]
  const float* w_qkv  = (const float*)d_in[1];  // [4096,12288]
  const float* w_proj = (const float*)d_in[2];  // [4096,4096]
  const float* b_proj = (const float*)d_in[3];  // [4096]
  float* out = (float*)d_out;

  char* ws = (char*)d_ws;
  ushort_t* xb     = (ushort_t*)(ws);                 // 33,554,432 B
  ushort_t* wqkvt  = (ushort_t*)(ws + 33554432ULL);   // 100,663,296 B  [12288][4096]
  ushort_t* wprojt = (ushort_t*)(ws + 134217728ULL);  // 33,554,432 B   [4096][4096]
  ushort_t* qkvb   = (ushort_t*)(ws + 167772160ULL);  // 100,663,296 B  [4096][12288]
  ushort_t* vt     = (ushort_t*)(ws + 268435456ULL);  // 33,554,432 B   [64][128][2048]
  ushort_t* ctx    = (ushort_t*)(ws + 301989888ULL);  // 33,554,432 B   [4096][4096]

  k_conv<<<16384, 256, 0, stream>>>(x, xb, 16777216 / 4);
  k_transpose_conv<<<dim3(192, 64), 256, 0, stream>>>(w_qkv, wqkvt, 4096, 12288);
  k_transpose_conv<<<dim3(64, 64), 256, 0, stream>>>(w_proj, wprojt, 4096, 4096);
  k_gemm_bt<true, true><<<dim3(48, 16), 512, 0, stream>>>(xb, wqkvt, qkvb, nullptr,
                                                          nullptr, 4096, 12288, 4096);
  k_build_vt<<<dim3(32, 64), 256, 0, stream>>>(qkvb, vt);
  k_attn<<<dim3(16, 64), 256, 0, stream>>>(qkvb, vt, ctx);
  k_gemm_bt<false, false><<<dim3(16, 16), 512, 0, stream>>>(ctx, wprojt, nullptr, out,
                                                            b_proj, 4096, 4096, 4096);
}

// Round 5
// 1270.961 us; speedup vs baseline: 1.2356x; 1.1436x over previous
//
#include <hip/hip_runtime.h>
#include <stdint.h>

typedef unsigned short ushort_t;
typedef __attribute__((ext_vector_type(8))) short s16x8;
typedef __attribute__((ext_vector_type(4))) float f32x4;
typedef __attribute__((ext_vector_type(4))) unsigned short u16x4;

#define DEV __device__ __forceinline__

DEV ushort_t f2bf(float f) {
  union { float f; uint32_t u; } v; v.f = f;
  uint32_t r = (v.u + 0x7FFFu + ((v.u >> 16) & 1u)) >> 16;
  return (ushort_t)r;
}
DEV float bf2f(ushort_t u) {
  union { uint32_t u; float f; } v; v.u = ((uint32_t)u) << 16;
  return v.f;
}

#define GLD_LDS16(g, l)                                     \
  __builtin_amdgcn_global_load_lds(                         \
      (const __attribute__((address_space(1))) void*)(g),   \
      (__attribute__((address_space(3))) void*)(l), 16, 0, 0)

#define MFMA16(a, b, c) __builtin_amdgcn_mfma_f32_16x16x32_bf16((a), (b), (c), 0, 0, 0)

// ---------------- fp32 -> bf16 elementwise ----------------
__global__ __launch_bounds__(256) void k_conv(const float* __restrict__ in,
                                              ushort_t* __restrict__ out, int n4) {
  int i = blockIdx.x * 256 + threadIdx.x;
  if (i >= n4) return;
  float4 v = ((const float4*)in)[i];
  u16x4 o;
  o[0] = f2bf(v.x); o[1] = f2bf(v.y); o[2] = f2bf(v.z); o[3] = f2bf(v.w);
  *((u16x4*)out + i) = o;
}

// ------------- fp32 [R][C] -> bf16 [C][R] tiled transpose -------------
__global__ __launch_bounds__(256) void k_transpose_conv(const float* __restrict__ in,
                                                        ushort_t* __restrict__ out,
                                                        int R, int C) {
  __shared__ float tile[64][65];
  int c0 = blockIdx.x * 64, r0 = blockIdx.y * 64;
  int t = threadIdx.x;
#pragma unroll
  for (int i = 0; i < 4; ++i) {
    int e = (i * 256 + t) * 4;
    int rr = e >> 6, cc = e & 63;
    float4 v = *(const float4*)(in + (size_t)(r0 + rr) * C + (c0 + cc));
    tile[rr][cc] = v.x; tile[rr][cc + 1] = v.y;
    tile[rr][cc + 2] = v.z; tile[rr][cc + 3] = v.w;
  }
  __syncthreads();
#pragma unroll
  for (int i = 0; i < 4; ++i) {
    int e = (i * 256 + t) * 4;
    int cc = e >> 6, rr = e & 63;
    u16x4 o;
    o[0] = f2bf(tile[rr][cc]);     o[1] = f2bf(tile[rr + 1][cc]);
    o[2] = f2bf(tile[rr + 2][cc]); o[3] = f2bf(tile[rr + 3][cc]);
    *(u16x4*)(out + (size_t)(c0 + cc) * R + (r0 + rr)) = o;
  }
}

// ---------------- GEMM: C[M][N] = A[M][K] * Bt[N][K]^T (bf16 in, fp32 acc) ----------------
// 256x256 tile, BK=32, 512 threads = 8 waves (2M x 4N), per-wave 128x64 output.
// ROUND-1 structure (measured 543us QKV, best of R0-R4): monolithic K-tile body,
// ONE barrier per K-tile, 4-deep LDS ring, prefetch distance 3, counted vmcnt(8)
// (never 0 in main loop), stage issues interleaved between the two 16-MFMA clusters,
// setprio around MFMA clusters. Phase-splitting this (R3/R4) regressed -13..-26%
// (m196-class: coarse split without fine interleave hurts).
// LDS chunk swizzle: chunk ^= (row>>1)&3 on global SOURCE (linear LDS dest) and
// identically on ds_read -> measured 0 bank conflicts.
// ROPE: fused interleaved rotary on epilogue fp32 acc for cols < 8192 (q,k sections).
template <bool BF16OUT, bool ROPE>
__global__ __launch_bounds__(512, 2) void k_gemm_bt(const ushort_t* __restrict__ A,
                                                    const ushort_t* __restrict__ Bt,
                                                    ushort_t* __restrict__ Cb,
                                                    float* __restrict__ Cf,
                                                    const float* __restrict__ bias,
                                                    int M, int N, int K) {
  // 4 bufs x 256 rows x 32 cols bf16 = 64 KiB each matrix, 128 KiB total
  __shared__ __align__(16) ushort_t lA[4 * 256 * 32];
  __shared__ __align__(16) ushort_t lB[4 * 256 * 32];
  int t = threadIdx.x;
  int wv = t >> 6, lane = t & 63, quad = lane >> 4, lrow = lane & 15;
  int wr = wv >> 2, wc = wv & 3;

  // XCD-bijective block swizzle (grid sizes here are multiples of 8)
  int nbx = gridDim.x;
  int nwg = nbx * gridDim.y;
  int id = blockIdx.y * nbx + blockIdx.x;
  int qq = nwg >> 3;
  int sw = (id & 7) * qq + (id >> 3);
  int n0 = (sw % nbx) * 256;
  int m0 = (sw / nbx) * 256;

  // ---- staging constants: 512 slots per half-tile, slot = tid, row = tid>>2,
  // chunk_slot = tid&3, pre-swizzled global chunk = cs ^ ((row>>1)&3) = cs ^ ((tid>>3)&3)
  int srow = t >> 2;
  int gch = (t & 3) ^ ((t >> 3) & 3);
  const ushort_t* gA0 = A + (size_t)(m0 + srow) * K + gch * 8;
  const ushort_t* gA1 = gA0 + (size_t)128 * K;
  const ushort_t* gB0 = Bt + (size_t)(n0 + srow) * K + gch * 8;
  const ushort_t* gB1 = gB0 + (size_t)128 * K;
  int ldst = wv * 512;  // wave-uniform LDS slot base (elements); +4096 for half 1

  // ---- ds_read constants: logical chunk = quad, stored chunk = quad ^ ((row>>1)&3);
  // (row>>1)&3 == (lrow>>1)&3 since row = base16 + lrow
  int xorv = (lrow >> 1) & 3;
  int aoff = (wr * 128 + lrow) * 32 + ((quad ^ xorv) * 8);
  int boff = (wc * 64 + lrow) * 32 + ((quad ^ xorv) * 8);

  f32x4 acc[8][4];
#pragma unroll
  for (int i = 0; i < 8; ++i)
#pragma unroll
    for (int j = 0; j < 4; ++j) acc[i][j] = (f32x4){0.f, 0.f, 0.f, 0.f};

  int nt = K >> 5;

  auto stageA = [&](int tt) {
    int buf = tt & 3;
    size_t ko = (size_t)tt * 32;
    ushort_t* la = lA + buf * 8192 + ldst;
    GLD_LDS16(gA0 + ko, la);
    GLD_LDS16(gA1 + ko, la + 4096);
  };
  auto stageB = [&](int tt) {
    int buf = tt & 3;
    size_t ko = (size_t)tt * 32;
    ushort_t* lb = lB + buf * 8192 + ldst;
    GLD_LDS16(gB0 + ko, lb);
    GLD_LDS16(gB1 + ko, lb + 4096);
  };

  // prologue: stage tiles 0,1,2 (12 loads/thread in flight)
  stageA(0); stageB(0);
  stageA(1); stageB(1);
  stageA(2); stageB(2);

#define TILE_BODY(BUFV, DOSTAGE, TT)                                     \
  {                                                                      \
    const ushort_t* ba = lA + (BUFV) * 8192;                             \
    const ushort_t* bb = lB + (BUFV) * 8192;                             \
    s16x8 af[4], bfr[4];                                                 \
    _Pragma("unroll") for (int j = 0; j < 4; ++j)                        \
        bfr[j] = *(const s16x8*)(bb + boff + j * 512);                   \
    _Pragma("unroll") for (int i = 0; i < 4; ++i)                        \
        af[i] = *(const s16x8*)(ba + aoff + i * 512);                    \
    if (DOSTAGE) stageA((TT) + 3);                                       \
    __builtin_amdgcn_s_setprio(1);                                       \
    _Pragma("unroll") for (int i = 0; i < 4; ++i)                        \
      _Pragma("unroll") for (int j = 0; j < 4; ++j)                      \
          acc[i][j] = MFMA16(af[i], bfr[j], acc[i][j]);                  \
    __builtin_amdgcn_s_setprio(0);                                       \
    _Pragma("unroll") for (int i = 0; i < 4; ++i)                        \
        af[i] = *(const s16x8*)(ba + aoff + (i + 4) * 512);              \
    if (DOSTAGE) stageB((TT) + 3);                                       \
    __builtin_amdgcn_s_setprio(1);                                       \
    _Pragma("unroll") for (int i = 0; i < 4; ++i)                        \
      _Pragma("unroll") for (int j = 0; j < 4; ++j)                      \
          acc[i + 4][j] = MFMA16(af[i], bfr[j], acc[i + 4][j]);          \
    __builtin_amdgcn_s_setprio(0);                                       \
  }

  // main loop: tile t's 4 loads are oldest of 12 outstanding -> vmcnt(8) lands them,
  // leaves 8 in flight across the barrier.
  for (int tt = 0; tt < nt - 2; ++tt) {
    asm volatile("s_waitcnt vmcnt(8)" ::: "memory");
    __builtin_amdgcn_s_barrier();
    TILE_BODY(tt & 3, (tt < nt - 3), tt);
  }
  asm volatile("s_waitcnt vmcnt(4)" ::: "memory");
  __builtin_amdgcn_s_barrier();
  TILE_BODY((nt - 2) & 3, false, nt - 2);
  asm volatile("s_waitcnt vmcnt(0)" ::: "memory");
  __builtin_amdgcn_s_barrier();
  TILE_BODY((nt - 1) & 3, false, nt - 1);
#undef TILE_BODY

  // ---- epilogue ----
  bool do_rope = ROPE && (n0 < 8192);   // block-uniform (8192 % 256 == 0)
  float sgn_sel = (lrow & 1) ? 1.f : -1.f;
#pragma unroll
  for (int j = 0; j < 4; ++j) {
    int gc = n0 + wc * 64 + j * 16 + lrow;
    float freq = 0.f;
    if (do_rope) {
      int p = (gc & 127) >> 1;
      freq = __expf(-(float)p * 0.14391156509165667f);  // ln(1e4)/64
    }
#pragma unroll
    for (int i = 0; i < 8; ++i)
#pragma unroll
      for (int r = 0; r < 4; ++r) {
        int gr = m0 + wr * 128 + i * 16 + quad * 4 + r;
        float val = acc[i][j][r];
        if (do_rope) {
          float other = __shfl_xor(val, 1);
          float sv, cv;
          sincosf((float)(gr & 2047) * freq, &sv, &cv);
          val = fmaf(other, sgn_sel * sv, val * cv);
        }
        if (BF16OUT)
          Cb[(size_t)gr * N + gc] = f2bf(val);
        else
          Cf[(size_t)gr * N + gc] = val + bias[gc];
      }
  }
}

// ---------------- build V^T: vt[b,h,d,s] from qkv v-section ----------------
__global__ __launch_bounds__(256) void k_build_vt(const ushort_t* __restrict__ qkv,
                                                  ushort_t* __restrict__ vt) {
  const int S = 2048;
  int s0 = blockIdx.x * 64;
  int bh = blockIdx.y;
  int b = bh >> 5, h = bh & 31;
  __shared__ ushort_t tl[64][136];
  int t = threadIdx.x;
  const ushort_t* src = qkv + (size_t)(b * S + s0) * 12288 + 8192 + h * 128;
#pragma unroll
  for (int i = 0; i < 4; ++i) {
    int e = (i * 256 + t) * 8;
    int row = e >> 7, col = e & 127;
    *(s16x8*)&tl[row][col] = *(const s16x8*)(src + (size_t)row * 12288 + col);
  }
  __syncthreads();
  ushort_t* dst = vt + (size_t)bh * 128 * S;
#pragma unroll
  for (int i = 0; i < 4; ++i) {
    int e = (i * 256 + t) * 8;
    int d = e >> 6, ss = e & 63;
    s16x8 o;
#pragma unroll
    for (int j = 0; j < 8; ++j) o[j] = (short)tl[ss + j][d];
    *(s16x8*)(dst + (size_t)d * S + s0 + ss) = o;
  }
}

// ---------------- causal flash attention ----------------
// grid: (S/128, B*H) with XCD-bijective swizzle of the flattened id (q-tiles of the
// same (b,h) co-locate per XCD L2). block 256 = 4 waves; wave wv owns q rows
// [q0+32wv, +32). Q in registers.
// K/V staged via global_load_lds into a 2-DEEP LDS RING with counted vmcnt:
// per iter {lgkmcnt(0)+barrier (WAR) -> stage(t+1) -> vmcnt(8) (tile t, issued a
// full iteration earlier, lands) -> barrier -> compute}. No vmcnt(0) drain in the
// main loop (last iter only). setprio(1) around QK and PV MFMA clusters.
// lP shrunk to [32][64] with per-row XOR chunk swizzle so LDS = 32+32+16 = 80 KiB
// exactly -> 2 blocks/CU retained.
__global__ __launch_bounds__(256, 2) void k_attn(const ushort_t* __restrict__ qkv,
                                                 const ushort_t* __restrict__ vt,
                                                 ushort_t* __restrict__ ctx) {
  const int S = 2048;
  int p = blockIdx.y * 16 + blockIdx.x;      // nwg = 1024, multiple of 8
  int w = (p & 7) * 128 + (p >> 3);          // bijective XCD chunking
  int qt = w & 15, bh = w >> 4;
  int b = bh >> 5, h = bh & 31;
  int q0 = qt * 128;
  int t = threadIdx.x;
  int wv = t >> 6, lane = t & 63, quad = lane >> 4, lrow = lane & 15;

  __shared__ __align__(16) ushort_t lK[2][64 * 128];  // [buf][kv][d], swizzled 16B chunks
  __shared__ __align__(16) ushort_t lV[2][128 * 64];  // [buf][d][kv], swizzled 16B chunks
  __shared__ __align__(16) ushort_t lP[4][32][64];    // per-wave P, XOR chunk swizzle

  const ushort_t* qp = qkv + (size_t)(b * S) * 12288 + h * 128;
  const ushort_t* kp = qp + 4096;
  const ushort_t* vp = vt + (size_t)bh * 128 * S;

  // Q fragments in registers (rope already applied by fused GEMM epilogue)
  s16x8 qf[2][4];
  int qrb = q0 + wv * 32;
#pragma unroll
  for (int ti = 0; ti < 2; ++ti)
#pragma unroll
    for (int ks = 0; ks < 4; ++ks)
      qf[ti][ks] = *(const s16x8*)(qp + (size_t)(qrb + ti * 16 + lrow) * 12288 +
                                   ks * 32 + quad * 8);

  f32x4 O[2][8];
#pragma unroll
  for (int ti = 0; ti < 2; ++ti)
#pragma unroll
    for (int f = 0; f < 8; ++f) O[ti][f] = (f32x4){0.f, 0.f, 0.f, 0.f};
  float m_i[2][4], l_i[2][4];
#pragma unroll
  for (int ti = 0; ti < 2; ++ti)
#pragma unroll
    for (int r = 0; r < 4; ++r) { m_i[ti][r] = -__builtin_inff(); l_i[ti][r] = 0.f; }

  const float scale = 0.08838834764831845f;  // 1/sqrt(128)
  int NT = qt * 2 + 2;                       // kv tiles of 64

  auto stage = [&](int tt) {
    int kv0 = tt * 64;
    int bo = (tt & 1) * 8192;
    int ck = lane & 15;
    int cv = lane & 7;
#pragma unroll
    for (int it = 0; it < 4; ++it) {
      int slot = wv * 4 + it;
      // K: 1024B = 4 rows of 256B; lane -> row slot*4+(lane>>4), chunk lane&15
      int rowk = slot * 4 + (lane >> 4);
      int cpk = (ck & 8) | ((ck & 7) ^ (rowk & 7));
      GLD_LDS16(kp + (size_t)(kv0 + rowk) * 12288 + cpk * 8, &lK[0][0] + bo + slot * 512);
      // V^T: 1024B = 8 rows of 128B; lane -> row slot*8+(lane>>3), chunk lane&7
      int rowv = slot * 8 + (lane >> 3);
      int cpv = cv ^ (rowv & 7);
      GLD_LDS16(vp + (size_t)rowv * S + kv0 + cpv * 8, &lV[0][0] + bo + slot * 512);
    }
  };

  stage(0);  // prologue: 8 loads/lane in flight

  for (int tt = 0; tt < NT; ++tt) {
    int kv0 = tt * 64;
    const ushort_t* Kb = &lK[tt & 1][0];
    const ushort_t* Vb = &lV[tt & 1][0];

    asm volatile("s_waitcnt lgkmcnt(0)" ::: "memory");
    __builtin_amdgcn_s_barrier();            // WAR: all waves done reading buf (tt+1)&1
    if (tt + 1 < NT) {                       // uniform branch
      stage(tt + 1);
      asm volatile("s_waitcnt vmcnt(8)" ::: "memory");   // tile tt landed (own 8 oldest)
    } else {
      asm volatile("s_waitcnt vmcnt(0)" ::: "memory");
    }
    __builtin_amdgcn_s_barrier();            // all waves' tile-tt data visible

    // S_tile = Q_tile @ K_tile^T
    f32x4 sc[2][4];
#pragma unroll
    for (int ti = 0; ti < 2; ++ti)
#pragma unroll
      for (int nt = 0; nt < 4; ++nt) sc[ti][nt] = (f32x4){0.f, 0.f, 0.f, 0.f};
#pragma unroll
    for (int ks = 0; ks < 4; ++ks) {
      s16x8 bk[4];
#pragma unroll
      for (int nt = 0; nt < 4; ++nt) {
        int row = nt * 16 + lrow;
        int cc = ks * 4 + quad;
        int cp = (cc & 8) | ((cc & 7) ^ (row & 7));
        bk[nt] = *(const s16x8*)(Kb + row * 128 + cp * 8);
      }
      __builtin_amdgcn_s_setprio(1);
#pragma unroll
      for (int ti = 0; ti < 2; ++ti)
#pragma unroll
        for (int nt = 0; nt < 4; ++nt) sc[ti][nt] = MFMA16(qf[ti][ks], bk[nt], sc[ti][nt]);
      __builtin_amdgcn_s_setprio(0);
    }

    // online softmax per 16-row tile (C layout: row = quad*4+r, col = lrow)
#pragma unroll
    for (int ti = 0; ti < 2; ++ti) {
      int qr = qrb + ti * 16 + quad * 4;
      float mt[4];
#pragma unroll
      for (int r = 0; r < 4; ++r) mt[r] = -__builtin_inff();
      float pvl[4][4];
#pragma unroll
      for (int nt = 0; nt < 4; ++nt) {
        int kc = kv0 + nt * 16 + lrow;
#pragma unroll
        for (int r = 0; r < 4; ++r) {
          float sv = sc[ti][nt][r] * scale;
          if (kc > qr + r) sv = -__builtin_inff();
          pvl[nt][r] = sv;
          mt[r] = fmaxf(mt[r], sv);
        }
      }
#pragma unroll
      for (int r = 0; r < 4; ++r)
#pragma unroll
        for (int off = 1; off < 16; off <<= 1)
          mt[r] = fmaxf(mt[r], __shfl_xor(mt[r], off, 16));

      float al[4], ls[4];
#pragma unroll
      for (int r = 0; r < 4; ++r) {
        float mn = fmaxf(m_i[ti][r], mt[r]);
        al[r] = __expf(m_i[ti][r] - mn);
        m_i[ti][r] = mn;
        ls[r] = 0.f;
      }
#pragma unroll
      for (int nt = 0; nt < 4; ++nt)
#pragma unroll
        for (int r = 0; r < 4; ++r) {
          float pexp = __expf(pvl[nt][r] - m_i[ti][r]);
          ushort_t pu = f2bf(pexp);
          int prow = quad * 4 + r;
          // chunk swizzle: logical chunk nt*2+(lrow>>3), stored chunk ^= prow&7
          lP[wv][ti * 16 + prow]
            [(((nt * 2 + (lrow >> 3)) ^ (prow & 7)) << 3) | (lrow & 7)] = pu;
          ls[r] += bf2f(pu);  // denominator from the same rounded P the PV mfma sees
        }
#pragma unroll
      for (int r = 0; r < 4; ++r) {
#pragma unroll
        for (int off = 1; off < 16; off <<= 1) ls[r] += __shfl_xor(ls[r], off, 16);
        l_i[ti][r] = al[r] * l_i[ti][r] + ls[r];
      }
#pragma unroll
      for (int f = 0; f < 8; ++f)
#pragma unroll
        for (int r = 0; r < 4; ++r) O[ti][f][r] *= al[r];
    }
    // NOTE: no barrier here — lP[wv] is same-wave write->read; lgkmcnt covers it.

    // O += P @ V
#pragma unroll
    for (int ks = 0; ks < 2; ++ks) {
      s16x8 pa[2];
#pragma unroll
      for (int ti = 0; ti < 2; ++ti)
        pa[ti] = *(const s16x8*)&lP[wv][ti * 16 + lrow]
                     [(((ks * 4 + quad) ^ (lrow & 7)) << 3)];
#pragma unroll
      for (int f = 0; f < 8; ++f) {
        int row = f * 16 + lrow;
        int cc = ks * 4 + quad;
        int cp = cc ^ (row & 7);
        s16x8 bv = *(const s16x8*)(Vb + row * 64 + cp * 8);
        __builtin_amdgcn_s_setprio(1);
#pragma unroll
        for (int ti = 0; ti < 2; ++ti) O[ti][f] = MFMA16(pa[ti], bv, O[ti][f]);
        __builtin_amdgcn_s_setprio(0);
      }
    }
  }

#pragma unroll
  for (int ti = 0; ti < 2; ++ti) {
    float inv[4];
#pragma unroll
    for (int r = 0; r < 4; ++r) inv[r] = 1.f / l_i[ti][r];
#pragma unroll
    for (int f = 0; f < 8; ++f)
#pragma unroll
      for (int r = 0; r < 4; ++r) {
        size_t idx = (size_t)(b * S + qrb + ti * 16 + quad * 4 + r) * 4096 +
                     h * 128 + f * 16 + lrow;
        ctx[idx] = f2bf(O[ti][f][r] * inv[r]);
      }
  }
}

// ---------------- launcher ----------------
extern "C" void kernel_launch(void* const* d_in, const int* in_sizes, int n_in,
                              void* d_out, int out_size, void* d_ws, size_t ws_size,
                              hipStream_t stream) {
  const float* x      = (const float*)d_in[0];  // [2,2048,4096]
  const float* w_qkv  = (const float*)d_in[1];  // [4096,12288]
  const float* w_proj = (const float*)d_in[2];  // [4096,4096]
  const float* b_proj = (const float*)d_in[3];  // [4096]
  float* out = (float*)d_out;

  char* ws = (char*)d_ws;
  ushort_t* xb     = (ushort_t*)(ws);                 // 33,554,432 B
  ushort_t* wqkvt  = (ushort_t*)(ws + 33554432ULL);   // 100,663,296 B  [12288][4096]
  ushort_t* wprojt = (ushort_t*)(ws + 134217728ULL);  // 33,554,432 B   [4096][4096]
  ushort_t* qkvb   = (ushort_t*)(ws + 167772160ULL);  // 100,663,296 B  [4096][12288]
  ushort_t* vt     = (ushort_t*)(ws + 268435456ULL);  // 33,554,432 B   [64][128][2048]
  ushort_t* ctx    = (ushort_t*)(ws + 301989888ULL);  // 33,554,432 B   [4096][4096]

  k_conv<<<16384, 256, 0, stream>>>(x, xb, 16777216 / 4);
  k_transpose_conv<<<dim3(192, 64), 256, 0, stream>>>(w_qkv, wqkvt, 4096, 12288);
  k_transpose_conv<<<dim3(64, 64), 256, 0, stream>>>(w_proj, wprojt, 4096, 4096);
  k_gemm_bt<true, true><<<dim3(48, 16), 512, 0, stream>>>(xb, wqkvt, qkvb, nullptr,
                                                          nullptr, 4096, 12288, 4096);
  k_build_vt<<<dim3(32, 64), 256, 0, stream>>>(qkvb, vt);
  k_attn<<<dim3(16, 64), 256, 0, stream>>>(qkvb, vt, ctx);
  k_gemm_bt<false, false><<<dim3(16, 16), 512, 0, stream>>>(ctx, wprojt, nullptr, out,
                                                            b_proj, 4096, 4096, 4096);
}